// Round 2
// baseline (855.139 us; speedup 1.0000x reference)
//
#include <hip/hip_runtime.h>
#include <math.h>

#define NPTS   500000
#define BROWS  256
#define DIMS   128
#define TILE_N 64
#define NTILES ((NPTS + TILE_N - 1) / TILE_N)  // 7813
#define NBLK   1024                            // gemm blocks, contiguous chunks
#define INV_T  (1.0f / 0.07f)

typedef _Float16 half8   __attribute__((ext_vector_type(8)));
typedef float    floatx4 __attribute__((ext_vector_type(4)));

// Kernel 1: L2-normalize the 256 point rows -> f16 A; zero the loss accumulator.
__global__ __launch_bounds__(64) void prep_kernel(const float* __restrict__ pts,
                                                  _Float16* __restrict__ A,
                                                  float* __restrict__ out) {
    const int b = blockIdx.x;   // one row per block
    const int t = threadIdx.x;  // 64 threads = 1 wave
    if (b == 0 && t == 0) out[0] = 0.0f;  // loss accumulator (finish_kernel atomicAdds)
    float x0 = pts[b * DIMS + t];
    float x1 = pts[b * DIMS + 64 + t];
    float ss = x0 * x0 + x1 * x1;
#pragma unroll
    for (int off = 32; off > 0; off >>= 1) ss += __shfl_xor(ss, off, 64);
    float inv = 1.0f / sqrtf(ss);  // reference has no eps
    A[b * DIMS + t]      = (_Float16)(x0 * inv);
    A[b * DIMS + 64 + t] = (_Float16)(x1 * inv);
}

// Kernel 2: S = A (256x128) * bank^T (128xN), fused per-row sum(exp(s/T)).
// Each block owns a CONTIGUOUS chunk of tiles: split-cacheline (+4B offset) S
// lines at tile boundaries stay within one block/XCD and merge in L2, instead
// of RMW-ing at HBM across XCDs (strided assignment put adjacent tiles on
// different blocks). One coalesced partial store per block at the end.
__global__ __launch_bounds__(256) void gemm_kernel(const float* __restrict__ bank,
                                                   const _Float16* __restrict__ A,
                                                   float* __restrict__ out,
                                                   float* __restrict__ partial) {
    __shared__ _Float16 Bs[TILE_N][DIMS + 8];  // +8 halfs pad: 2-way banks only (free)
    __shared__ float    P[BROWS];
    const int tid = threadIdx.x;
    const int w = tid >> 6;
    const int l = tid & 63;
    const int q = l >> 4;   // quad
    const int c = l & 15;
    const int mbase = w * 64;   // wave w owns rows [64w, 64w+64)

    // A fragments once per block (64 KB workspace, L2/L3-hot). A[m=lane&15][k=q*8+j].
    half8 a[4][4];
#pragma unroll
    for (int mt = 0; mt < 4; mt++)
#pragma unroll
        for (int ks = 0; ks < 4; ks++)
            a[mt][ks] = *(const half8*)(A + (mbase + mt * 16 + c) * DIMS + ks * 32 + q * 8);

    float psum[4][4];  // [mt][r] running sum of exp over this block's columns
#pragma unroll
    for (int mt = 0; mt < 4; mt++)
#pragma unroll
        for (int r = 0; r < 4; r++) psum[mt][r] = 0.0f;

    float* S = out + 1;  // out[0] is the loss

    // Contiguous chunk [t0, t1) for this block.
    const int t0 = (int)(((long)blockIdx.x * NTILES) / NBLK);
    const int t1 = (int)(((long)(blockIdx.x + 1) * NTILES) / NBLK);

    for (int tile = t0; tile < t1; ++tile) {
        const long n0 = (long)tile * TILE_N;
        const bool full = (n0 + TILE_N <= NPTS);  // only the global last tile is partial

        // Stage bank tile (64 rows x 128 f32) -> f16 LDS, coalesced float4.
        {
            const float* src = bank + n0 * DIMS;
            if (full) {
#pragma unroll
                for (int i = 0; i < 8; i++) {
                    int f   = (i * 256 + tid) * 4;  // flat f32 index in tile
                    floatx4 v = *(const floatx4*)(src + f);
                    int row = f >> 7;
                    int col = f & 127;
                    _Float16* dst = &Bs[row][col];
                    dst[0] = (_Float16)v[0];
                    dst[1] = (_Float16)v[1];
                    dst[2] = (_Float16)v[2];
                    dst[3] = (_Float16)v[3];
                }
            } else {
#pragma unroll
                for (int i = 0; i < 8; i++) {
                    int f   = (i * 256 + tid) * 4;
                    int row = f >> 7;
                    int col = f & 127;
                    floatx4 v = {0.f, 0.f, 0.f, 0.f};
                    if (n0 + row < NPTS) v = *(const floatx4*)(src + f);
                    _Float16* dst = &Bs[row][col];
                    dst[0] = (_Float16)v[0];
                    dst[1] = (_Float16)v[1];
                    dst[2] = (_Float16)v[2];
                    dst[3] = (_Float16)v[3];
                }
            }
        }
        __syncthreads();

        floatx4 acc[4][4];
#pragma unroll
        for (int mt = 0; mt < 4; mt++)
#pragma unroll
            for (int nt = 0; nt < 4; nt++)
                acc[mt][nt] = (floatx4){0.f, 0.f, 0.f, 0.f};

#pragma unroll
        for (int ks = 0; ks < 4; ks++) {
            half8 bf[4];  // B[k][n=lane&15] = bank[n][k] -> 16B LDS reads
#pragma unroll
            for (int nt = 0; nt < 4; nt++)
                bf[nt] = *(const half8*)(&Bs[nt * 16 + c][ks * 32 + q * 8]);
#pragma unroll
            for (int mt = 0; mt < 4; mt++)
#pragma unroll
                for (int nt = 0; nt < 4; nt++)
                    acc[mt][nt] = __builtin_amdgcn_mfma_f32_16x16x32_f16(a[mt][ks], bf[nt],
                                                                         acc[mt][nt], 0, 0, 0);
        }

        // Epilogue: C/D layout col=lane&15, row=q*4+reg. Write S, accumulate exps.
        if (full) {
#pragma unroll
            for (int mt = 0; mt < 4; mt++) {
#pragma unroll
                for (int r = 0; r < 4; r++) {
                    const int m = mbase + mt * 16 + q * 4 + r;
                    float* Srow = S + (long)m * NPTS + n0;
                    float ps = 0.0f;
#pragma unroll
                    for (int nt = 0; nt < 4; nt++) {
                        float s = acc[mt][nt][r];
                        Srow[nt * 16 + c] = s;
                        ps += __expf(s * INV_T);  // <= exp(78.6) ~ 1.3e34, fits f32
                    }
                    psum[mt][r] += ps;
                }
            }
        } else {
#pragma unroll
            for (int mt = 0; mt < 4; mt++) {
#pragma unroll
                for (int r = 0; r < 4; r++) {
                    const int m = mbase + mt * 16 + q * 4 + r;
                    float ps = 0.0f;
#pragma unroll
                    for (int nt = 0; nt < 4; nt++) {
                        long n = n0 + nt * 16 + c;
                        if (n < NPTS) {
                            float s = acc[mt][nt][r];
                            S[(long)m * NPTS + n] = s;
                            ps += __expf(s * INV_T);
                        }
                    }
                    psum[mt][r] += ps;
                }
            }
        }
        __syncthreads();  // protect Bs before next tile's staging
    }

    // Block-level reduce: 16 quad lanes hold this row's column partials.
#pragma unroll
    for (int mt = 0; mt < 4; mt++) {
#pragma unroll
        for (int r = 0; r < 4; r++) {
            float v = psum[mt][r];
#pragma unroll
            for (int off = 1; off < 16; off <<= 1) v += __shfl_xor(v, off, 64);
            if (c == 0) P[mbase + mt * 16 + q * 4 + r] = v;
        }
    }
    __syncthreads();
    partial[(long)blockIdx.x * BROWS + tid] = P[tid];  // coalesced 1 KB store
}

// Kernel 3 (fused reduce + loss): block r sums partial[:, r] -> denom, then
// adds its row's -log(pos/denom + eps)/256 term into out[0] (zeroed by prep).
__global__ __launch_bounds__(256) void finish_kernel(const float* __restrict__ partial,
                                                     const int* __restrict__ idx,
                                                     float* __restrict__ out) {
    const int r = blockIdx.x;
    const int t = threadIdx.x;
    float s = 0.0f;
    for (int b = t; b < NBLK; b += 256) s += partial[(long)b * BROWS + r];
#pragma unroll
    for (int off = 32; off > 0; off >>= 1) s += __shfl_xor(s, off, 64);
    __shared__ float red[4];
    if ((t & 63) == 0) red[t >> 6] = s;
    __syncthreads();
    if (t == 0) {
        float denom = red[0] + red[1] + red[2] + red[3];
        const float* S = out + 1;
        float sv  = S[(long)r * NPTS + (long)idx[r]];
        float pos = __expf(sv * INV_T);
        float lg  = logf(pos / denom + 1e-7f);
        atomicAdd(out, -lg * (1.0f / 256.0f));
    }
}

extern "C" void kernel_launch(void* const* d_in, const int* in_sizes, int n_in,
                              void* d_out, int out_size, void* d_ws, size_t ws_size,
                              hipStream_t stream) {
    const float* points        = (const float*)d_in[0];
    const int*   point_indices = (const int*)d_in[1];  // JAX x64 off -> int32
    const float* bank          = (const float*)d_in[2];
    float* out = (float*)d_out;

    // ws layout: A (64 KB) | partial (1 MB)
    _Float16* A       = (_Float16*)d_ws;
    float*    partial = (float*)((char*)d_ws + 65536);

    prep_kernel<<<BROWS, 64, 0, stream>>>(points, A, out);
    gemm_kernel<<<NBLK, 256, 0, stream>>>(bank, A, out, partial);
    finish_kernel<<<BROWS, 256, 0, stream>>>(partial, point_indices, out);
}

// Round 3
// 804.230 us; speedup vs baseline: 1.0633x; 1.0633x over previous
//
#include <hip/hip_runtime.h>
#include <math.h>

#define NPTS   500000
#define BROWS  256
#define DIMS   128
#define TILE_N 64
#define NTILES ((NPTS + TILE_N - 1) / TILE_N)  // 7813
#define NBLK   1024                            // persistent gemm blocks, strided tiles
#define INV_T  (1.0f / 0.07f)

typedef _Float16 half8   __attribute__((ext_vector_type(8)));
typedef float    floatx4 __attribute__((ext_vector_type(4)));

// Kernel 1: L2-normalize the 256 point rows -> f16 A; zero the loss accumulator.
__global__ __launch_bounds__(64) void prep_kernel(const float* __restrict__ pts,
                                                  _Float16* __restrict__ A,
                                                  float* __restrict__ out) {
    const int b = blockIdx.x;   // one row per block
    const int t = threadIdx.x;  // 64 threads = 1 wave
    if (b == 0 && t == 0) out[0] = 0.0f;  // loss accumulator (finish_kernel atomicAdds)
    float x0 = pts[b * DIMS + t];
    float x1 = pts[b * DIMS + 64 + t];
    float ss = x0 * x0 + x1 * x1;
#pragma unroll
    for (int off = 32; off > 0; off >>= 1) ss += __shfl_xor(ss, off, 64);
    float inv = 1.0f / sqrtf(ss);  // reference has no eps
    A[b * DIMS + t]      = (_Float16)(x0 * inv);
    A[b * DIMS + 64 + t] = (_Float16)(x1 * inv);
}

// Kernel 2: S = A (256x128) * bank^T (128xN), fused per-row sum(exp(s/T)).
// STRIDED tile order (measured faster than chunked: whole chip marches a
// contiguous 32MB window -> DRAM locality). Double-buffered LDS with
// register-staged prefetch: tile t+1's global loads are issued BEFORE tile t's
// compute, converted/written to the other LDS buffer after the epilogue.
// One barrier per tile. Loads stay outstanding under compute (Little's law fix
// for the measured 1.9 TB/s / 24%-peak concurrency stall).
__global__ __launch_bounds__(256) void gemm_kernel(const float* __restrict__ bank,
                                                   const _Float16* __restrict__ A,
                                                   float* __restrict__ out,
                                                   float* __restrict__ partial) {
    __shared__ _Float16 Bs[2][TILE_N][DIMS + 8];  // 2 x 17 KB, +8 halfs pad
    __shared__ float    P[BROWS];
    const int tid = threadIdx.x;
    const int w = tid >> 6;
    const int l = tid & 63;
    const int q = l >> 4;   // quad
    const int c = l & 15;
    const int mbase = w * 64;   // wave w owns rows [64w, 64w+64)

    // A fragments once per block (64 KB workspace, L2/L3-hot). A[m=lane&15][k=q*8+j].
    half8 a[4][4];
#pragma unroll
    for (int mt = 0; mt < 4; mt++)
#pragma unroll
        for (int ks = 0; ks < 4; ks++)
            a[mt][ks] = *(const half8*)(A + (mbase + mt * 16 + c) * DIMS + ks * 32 + q * 8);

    float psum[4][4];  // [mt][r] running sum of exp over this block's columns
#pragma unroll
    for (int mt = 0; mt < 4; mt++)
#pragma unroll
        for (int r = 0; r < 4; r++) psum[mt][r] = 0.0f;

    float* S = out + 1;  // out[0] is the loss

    floatx4 ld[8];  // register staging for the in-flight tile (32 VGPR)

    // Prologue: stage first tile into Bs[0].
    {
        const long n0 = (long)blockIdx.x * TILE_N;
        const float* src = bank + n0 * DIMS;
        const bool full = (n0 + TILE_N <= NPTS);
#pragma unroll
        for (int i = 0; i < 8; i++) {
            int f = (i * 256 + tid) * 4;
            if (full || n0 + (f >> 7) < NPTS) ld[i] = *(const floatx4*)(src + f);
            else                              ld[i] = (floatx4){0.f, 0.f, 0.f, 0.f};
        }
#pragma unroll
        for (int i = 0; i < 8; i++) {
            int f = (i * 256 + tid) * 4;
            int row = f >> 7, col = f & 127;
            _Float16* dst = &Bs[0][row][col];
            dst[0] = (_Float16)ld[i][0];
            dst[1] = (_Float16)ld[i][1];
            dst[2] = (_Float16)ld[i][2];
            dst[3] = (_Float16)ld[i][3];
        }
    }
    __syncthreads();

    int cur = 0;
    for (int tile = blockIdx.x; tile < NTILES; tile += NBLK) {
        const long n0 = (long)tile * TILE_N;
        const bool full = (n0 + TILE_N <= NPTS);  // only global last tile is partial
        const int  nxt = tile + NBLK;
        const bool has_next = (nxt < NTILES);

        // Issue next tile's global loads NOW; vmcnt wait happens at the LDS
        // write after compute -> HBM latency hides under MFMA + epilogue.
        if (has_next) {
            const long nn0 = (long)nxt * TILE_N;
            const float* src = bank + nn0 * DIMS;
            const bool nfull = (nn0 + TILE_N <= NPTS);
#pragma unroll
            for (int i = 0; i < 8; i++) {
                int f = (i * 256 + tid) * 4;
                if (nfull || nn0 + (f >> 7) < NPTS) ld[i] = *(const floatx4*)(src + f);
                else                                ld[i] = (floatx4){0.f, 0.f, 0.f, 0.f};
            }
        }

        // Compute from Bs[cur].
        floatx4 acc[4][4];
#pragma unroll
        for (int mt = 0; mt < 4; mt++)
#pragma unroll
            for (int nt = 0; nt < 4; nt++)
                acc[mt][nt] = (floatx4){0.f, 0.f, 0.f, 0.f};

#pragma unroll
        for (int ks = 0; ks < 4; ks++) {
            half8 bf[4];  // B[k][n=lane&15] = bank[n][k] -> 16B LDS reads
#pragma unroll
            for (int nt = 0; nt < 4; nt++)
                bf[nt] = *(const half8*)(&Bs[cur][nt * 16 + c][ks * 32 + q * 8]);
#pragma unroll
            for (int mt = 0; mt < 4; mt++)
#pragma unroll
                for (int nt = 0; nt < 4; nt++)
                    acc[mt][nt] = __builtin_amdgcn_mfma_f32_16x16x32_f16(a[mt][ks], bf[nt],
                                                                         acc[mt][nt], 0, 0, 0);
        }

        // Epilogue: C/D layout col=lane&15, row=q*4+reg. Write S, accumulate exps.
        if (full) {
#pragma unroll
            for (int mt = 0; mt < 4; mt++) {
#pragma unroll
                for (int r = 0; r < 4; r++) {
                    const int m = mbase + mt * 16 + q * 4 + r;
                    float* Srow = S + (long)m * NPTS + n0;
                    float ps = 0.0f;
#pragma unroll
                    for (int nt = 0; nt < 4; nt++) {
                        float s = acc[mt][nt][r];
                        Srow[nt * 16 + c] = s;
                        ps += __expf(s * INV_T);  // <= exp(78.6) ~ 1.3e34, fits f32
                    }
                    psum[mt][r] += ps;
                }
            }
        } else {
#pragma unroll
            for (int mt = 0; mt < 4; mt++) {
#pragma unroll
                for (int r = 0; r < 4; r++) {
                    const int m = mbase + mt * 16 + q * 4 + r;
                    float ps = 0.0f;
#pragma unroll
                    for (int nt = 0; nt < 4; nt++) {
                        long n = n0 + nt * 16 + c;
                        if (n < NPTS) {
                            float s = acc[mt][nt][r];
                            S[(long)m * NPTS + n] = s;
                            ps += __expf(s * INV_T);
                        }
                    }
                    psum[mt][r] += ps;
                }
            }
        }

        // Stage prefetched tile into the OTHER buffer (no conflict with the
        // reads above -> single barrier per iteration).
        if (has_next) {
#pragma unroll
            for (int i = 0; i < 8; i++) {
                int f = (i * 256 + tid) * 4;
                int row = f >> 7, col = f & 127;
                _Float16* dst = &Bs[cur ^ 1][row][col];
                dst[0] = (_Float16)ld[i][0];
                dst[1] = (_Float16)ld[i][1];
                dst[2] = (_Float16)ld[i][2];
                dst[3] = (_Float16)ld[i][3];
            }
        }
        __syncthreads();
        cur ^= 1;
    }

    // Block-level reduce: 16 quad lanes hold this row's column partials.
#pragma unroll
    for (int mt = 0; mt < 4; mt++) {
#pragma unroll
        for (int r = 0; r < 4; r++) {
            float v = psum[mt][r];
#pragma unroll
            for (int off = 1; off < 16; off <<= 1) v += __shfl_xor(v, off, 64);
            if (c == 0) P[mbase + mt * 16 + q * 4 + r] = v;
        }
    }
    __syncthreads();
    partial[(long)blockIdx.x * BROWS + tid] = P[tid];  // coalesced 1 KB store
}

// Kernel 3 (fused reduce + loss): block r sums partial[:, r] -> denom, then
// adds its row's -log(pos/denom + eps)/256 term into out[0] (zeroed by prep).
__global__ __launch_bounds__(256) void finish_kernel(const float* __restrict__ partial,
                                                     const int* __restrict__ idx,
                                                     float* __restrict__ out) {
    const int r = blockIdx.x;
    const int t = threadIdx.x;
    float s = 0.0f;
    for (int b = t; b < NBLK; b += 256) s += partial[(long)b * BROWS + r];
#pragma unroll
    for (int off = 32; off > 0; off >>= 1) s += __shfl_xor(s, off, 64);
    __shared__ float red[4];
    if ((t & 63) == 0) red[t >> 6] = s;
    __syncthreads();
    if (t == 0) {
        float denom = red[0] + red[1] + red[2] + red[3];
        const float* S = out + 1;
        float sv  = S[(long)r * NPTS + (long)idx[r]];
        float pos = __expf(sv * INV_T);
        float lg  = logf(pos / denom + 1e-7f);
        atomicAdd(out, -lg * (1.0f / 256.0f));
    }
}

extern "C" void kernel_launch(void* const* d_in, const int* in_sizes, int n_in,
                              void* d_out, int out_size, void* d_ws, size_t ws_size,
                              hipStream_t stream) {
    const float* points        = (const float*)d_in[0];
    const int*   point_indices = (const int*)d_in[1];  // JAX x64 off -> int32
    const float* bank          = (const float*)d_in[2];
    float* out = (float*)d_out;

    // ws layout: A (64 KB) | partial (1 MB)
    _Float16* A       = (_Float16*)d_ws;
    float*    partial = (float*)((char*)d_ws + 65536);

    prep_kernel<<<BROWS, 64, 0, stream>>>(points, A, out);
    gemm_kernel<<<NBLK, 256, 0, stream>>>(bank, A, out, partial);
    finish_kernel<<<BROWS, 256, 0, stream>>>(partial, point_indices, out);
}

// Round 4
// 794.543 us; speedup vs baseline: 1.0763x; 1.0122x over previous
//
#include <hip/hip_runtime.h>
#include <math.h>

#define NPTS   500000
#define BROWS  256
#define DIMS   128
#define TILE_N 256
#define NTILES ((NPTS + TILE_N - 1) / TILE_N)  // 1954
#define INV_T  (1.0f / 0.07f)

typedef _Float16 half8   __attribute__((ext_vector_type(8)));
typedef float    floatx4 __attribute__((ext_vector_type(4)));

// Kernel 1: L2-normalize the 256 point rows -> f16 A; zero the loss accumulator.
__global__ __launch_bounds__(64) void prep_kernel(const float* __restrict__ pts,
                                                  _Float16* __restrict__ A,
                                                  float* __restrict__ out) {
    const int b = blockIdx.x;   // one row per block
    const int t = threadIdx.x;  // 64 threads = 1 wave
    if (b == 0 && t == 0) out[0] = 0.0f;  // loss accumulator (finish_kernel atomicAdds)
    float x0 = pts[b * DIMS + t];
    float x1 = pts[b * DIMS + 64 + t];
    float ss = x0 * x0 + x1 * x1;
#pragma unroll
    for (int off = 32; off > 0; off >>= 1) ss += __shfl_xor(ss, off, 64);
    float inv = 1.0f / sqrtf(ss);  // reference has no eps
    A[b * DIMS + t]      = (_Float16)(x0 * inv);
    A[b * DIMS + 64 + t] = (_Float16)(x1 * inv);
}

// Kernel 2: one block per 256-column tile of S (grid 1954, dispatch order gives
// the chip-wide marching read window). WHY 256 wide: S rows are 2MB apart, so
// each tile's per-row write is the unit of DRAM page locality. At TILE_N=64 a
// block wrote 256B/row (quarter-page, 4 visits per page by different blocks ->
// measured 2.2 TB/s, 35% eff). At 256 each row gets a full 1KB HBM page,
// written back-to-back -> full-line, full-page streaming.
__global__ __launch_bounds__(256) void gemm_kernel(const float* __restrict__ bank,
                                                   const _Float16* __restrict__ A,
                                                   float* __restrict__ out,
                                                   float* __restrict__ partial) {
    __shared__ _Float16 Bs[TILE_N][DIMS + 8];  // 256 x 136 halfs = 68 KB, pad: 2-way banks
    __shared__ float    P[BROWS];
    const int tid = threadIdx.x;
    const int w = tid >> 6;
    const int l = tid & 63;
    const int q = l >> 4;   // quad
    const int c = l & 15;
    const int mbase = w * 64;   // wave w owns rows [64w, 64w+64)

    // A fragments (64 KB workspace, L2-hot after first blocks). A[m=lane&15][k=q*8+j].
    half8 a[4][4];
#pragma unroll
    for (int mt = 0; mt < 4; mt++)
#pragma unroll
        for (int ks = 0; ks < 4; ks++)
            a[mt][ks] = *(const half8*)(A + (mbase + mt * 16 + c) * DIMS + ks * 32 + q * 8);

    float psum[4][4];  // [mt][r] running sum of exp over this tile's columns
#pragma unroll
    for (int mt = 0; mt < 4; mt++)
#pragma unroll
        for (int r = 0; r < 4; r++) psum[mt][r] = 0.0f;

    float* S = out + 1;  // out[0] is the loss

    const long n0 = (long)blockIdx.x * TILE_N;
    const bool full = (n0 + TILE_N <= NPTS);  // only tile 1953 is partial (32 cols)

    // Stage bank tile (256 rows x 128 f32 = 128 KB, sequential) -> f16 LDS.
    {
        const float* src = bank + n0 * DIMS;
        if (full) {
#pragma unroll
            for (int i = 0; i < 32; i++) {
                int f = (i * 256 + tid) * 4;  // flat f32 index in tile
                floatx4 v = *(const floatx4*)(src + f);
                int row = f >> 7, col = f & 127;
                _Float16* dst = &Bs[row][col];
                dst[0] = (_Float16)v[0];
                dst[1] = (_Float16)v[1];
                dst[2] = (_Float16)v[2];
                dst[3] = (_Float16)v[3];
            }
        } else {
#pragma unroll
            for (int i = 0; i < 32; i++) {
                int f = (i * 256 + tid) * 4;
                int row = f >> 7, col = f & 127;
                floatx4 v = {0.f, 0.f, 0.f, 0.f};
                if (n0 + row < NPTS) v = *(const floatx4*)(src + f);
                _Float16* dst = &Bs[row][col];
                dst[0] = (_Float16)v[0];
                dst[1] = (_Float16)v[1];
                dst[2] = (_Float16)v[2];
                dst[3] = (_Float16)v[3];
            }
        }
    }
    __syncthreads();

    // 4 n-groups of 64 columns; each row's 1KB is emitted in 4 adjacent bursts.
    for (int ntg = 0; ntg < 4; ntg++) {
        floatx4 acc[4][4];
#pragma unroll
        for (int mt = 0; mt < 4; mt++)
#pragma unroll
            for (int nt = 0; nt < 4; nt++)
                acc[mt][nt] = (floatx4){0.f, 0.f, 0.f, 0.f};

#pragma unroll
        for (int ks = 0; ks < 4; ks++) {
            half8 bf[4];  // B[k][n=lane&15] -> 16B LDS reads
#pragma unroll
            for (int nt = 0; nt < 4; nt++)
                bf[nt] = *(const half8*)(&Bs[ntg * 64 + nt * 16 + c][ks * 32 + q * 8]);
#pragma unroll
            for (int mt = 0; mt < 4; mt++)
#pragma unroll
                for (int nt = 0; nt < 4; nt++)
                    acc[mt][nt] = __builtin_amdgcn_mfma_f32_16x16x32_f16(a[mt][ks], bf[nt],
                                                                         acc[mt][nt], 0, 0, 0);
        }

        // Epilogue: C/D layout col=lane&15, row=q*4+reg. Write S, accumulate exps.
        if (full) {
#pragma unroll
            for (int mt = 0; mt < 4; mt++) {
#pragma unroll
                for (int r = 0; r < 4; r++) {
                    const int m = mbase + mt * 16 + q * 4 + r;
                    float* Srow = S + (long)m * NPTS + n0 + ntg * 64;
                    float ps = 0.0f;
#pragma unroll
                    for (int nt = 0; nt < 4; nt++) {
                        float s = acc[mt][nt][r];
                        Srow[nt * 16 + c] = s;
                        ps += __expf(s * INV_T);  // <= exp(78.6) ~ 1.3e34, fits f32
                    }
                    psum[mt][r] += ps;
                }
            }
        } else {
#pragma unroll
            for (int mt = 0; mt < 4; mt++) {
#pragma unroll
                for (int r = 0; r < 4; r++) {
                    const int m = mbase + mt * 16 + q * 4 + r;
                    float ps = 0.0f;
#pragma unroll
                    for (int nt = 0; nt < 4; nt++) {
                        long n = n0 + ntg * 64 + nt * 16 + c;
                        if (n < NPTS) {
                            float s = acc[mt][nt][r];
                            S[(long)m * NPTS + n] = s;
                            ps += __expf(s * INV_T);
                        }
                    }
                    psum[mt][r] += ps;
                }
            }
        }
    }

    // Block-level reduce: 16 quad lanes hold this row's column partials.
#pragma unroll
    for (int mt = 0; mt < 4; mt++) {
#pragma unroll
        for (int r = 0; r < 4; r++) {
            float v = psum[mt][r];
#pragma unroll
            for (int off = 1; off < 16; off <<= 1) v += __shfl_xor(v, off, 64);
            if (c == 0) P[mbase + mt * 16 + q * 4 + r] = v;
        }
    }
    __syncthreads();
    partial[(long)blockIdx.x * BROWS + tid] = P[tid];  // coalesced 1 KB store
}

// Kernel 3 (fused reduce + loss): block r sums partial[:, r] -> denom, then
// adds its row's -log(pos/denom + eps)/256 term into out[0] (zeroed by prep).
__global__ __launch_bounds__(256) void finish_kernel(const float* __restrict__ partial,
                                                     const int* __restrict__ idx,
                                                     float* __restrict__ out) {
    const int r = blockIdx.x;
    const int t = threadIdx.x;
    float s = 0.0f;
    for (int b = t; b < NTILES; b += 256) s += partial[(long)b * BROWS + r];
#pragma unroll
    for (int off = 32; off > 0; off >>= 1) s += __shfl_xor(s, off, 64);
    __shared__ float red[4];
    if ((t & 63) == 0) red[t >> 6] = s;
    __syncthreads();
    if (t == 0) {
        float denom = red[0] + red[1] + red[2] + red[3];
        const float* S = out + 1;
        float sv  = S[(long)r * NPTS + (long)idx[r]];
        float pos = __expf(sv * INV_T);
        float lg  = logf(pos / denom + 1e-7f);
        atomicAdd(out, -lg * (1.0f / 256.0f));
    }
}

extern "C" void kernel_launch(void* const* d_in, const int* in_sizes, int n_in,
                              void* d_out, int out_size, void* d_ws, size_t ws_size,
                              hipStream_t stream) {
    const float* points        = (const float*)d_in[0];
    const int*   point_indices = (const int*)d_in[1];  // JAX x64 off -> int32
    const float* bank          = (const float*)d_in[2];
    float* out = (float*)d_out;

    // ws layout: A (64 KB) | partial (1954*256*4 = ~1.91 MB)
    _Float16* A       = (_Float16*)d_ws;
    float*    partial = (float*)((char*)d_ws + 65536);

    prep_kernel<<<BROWS, 64, 0, stream>>>(points, A, out);
    gemm_kernel<<<NTILES, 256, 0, stream>>>(bank, A, out, partial);
    finish_kernel<<<BROWS, 256, 0, stream>>>(partial, point_indices, out);
}